// Round 11
// baseline (740.028 us; speedup 1.0000x reference)
//
#include <hip/hip_runtime.h>
#include <hip/hip_fp16.h>
#include <math.h>

#define C 16
#define FIN 128

typedef unsigned int u32x2 __attribute__((ext_vector_type(2)));
typedef float f32x4 __attribute__((ext_vector_type(4)));

// ---------------- GEMM x@W1 (100k x 128 x 16) + fused a_s/a_d ----------------
__global__ __launch_bounds__(256) void k_gemm1(
    const float* __restrict__ x, const float* __restrict__ W,
    const float* __restrict__ asw, const float* __restrict__ adw,
    __half* __restrict__ hh, float* __restrict__ a_s, float* __restrict__ a_d, int n) {
  __shared__ float xs[64 * 129];
  __shared__ float Ws[FIN * C];
  __shared__ float pAs[4][64], pAd[4][64];
  int t = threadIdx.x;
  int node0 = blockIdx.x * 64;
  for (int i = t; i < FIN * C; i += 256) Ws[i] = W[i];
  for (int i = t; i < 64 * FIN; i += 256) {
    int r = i >> 7, c = i & 127;
    int node = node0 + r;
    xs[r * 129 + c] = (node < n) ? x[(size_t)node * FIN + c] : 0.f;
  }
  __syncthreads();
  int nn = t & 63, cg = (t >> 6) * 4, grp = t >> 6;
  float a0 = 0.f, a1 = 0.f, a2 = 0.f, a3 = 0.f;
  const float* xr = &xs[nn * 129];
  #pragma unroll 8
  for (int k = 0; k < FIN; ++k) {
    float xv = xr[k];
    const float* wr = &Ws[k * C + cg];
    a0 += xv * wr[0]; a1 += xv * wr[1]; a2 += xv * wr[2]; a3 += xv * wr[3];
  }
  int node = node0 + nn;
  if (node < n) {
    __half2 p0 = __floats2half2_rn(a0, a1), p1 = __floats2half2_rn(a2, a3);
    unsigned u0, u1;
    memcpy(&u0, &p0, 4); memcpy(&u1, &p1, 4);
    *(uint2*)(hh + (size_t)node * 16 + cg) = make_uint2(u0, u1);
  }
  pAs[grp][nn] = a0 * asw[cg] + a1 * asw[cg + 1] + a2 * asw[cg + 2] + a3 * asw[cg + 3];
  pAd[grp][nn] = a0 * adw[cg] + a1 * adw[cg + 1] + a2 * adw[cg + 2] + a3 * adw[cg + 3];
  __syncthreads();
  if (t < 64 && node0 + t < n) {
    a_s[node0 + t] = pAs[0][t] + pAs[1][t] + pAs[2][t] + pAs[3][t];
    a_d[node0 + t] = pAd[0][t] + pAd[1][t] + pAd[2][t] + pAd[3][t];
  }
}

// ---------------- generic scan kernels ----------------
__global__ __launch_bounds__(512) void k_scan1(const int* __restrict__ counts,
                                               int* __restrict__ bsum, int n) {
  __shared__ int sd[512];
  int i = blockIdx.x * 512 + threadIdx.x;
  sd[threadIdx.x] = (i < n) ? counts[i] : 0;
  __syncthreads();
  for (int s = 256; s > 0; s >>= 1) {
    if (threadIdx.x < s) sd[threadIdx.x] += sd[threadIdx.x + s];
    __syncthreads();
  }
  if (threadIdx.x == 0) bsum[blockIdx.x] = sd[0];
}

__global__ __launch_bounds__(512) void k_scan2(int* __restrict__ bsum,
                                               int* __restrict__ offs,
                                               int nblk, int n) {
  __shared__ int sd[512];
  int t = threadIdx.x;
  int v = (t < nblk) ? bsum[t] : 0;
  sd[t] = v;
  __syncthreads();
  for (int off = 1; off < 512; off <<= 1) {
    int x = (t >= off) ? sd[t - off] : 0;
    __syncthreads();
    sd[t] += x;
    __syncthreads();
  }
  if (t < nblk) bsum[t] = sd[t] - v;
  if (t == nblk - 1) offs[n] = sd[t];
}

__global__ __launch_bounds__(512) void k_scan3(const int* __restrict__ counts,
                                               const int* __restrict__ bsum,
                                               int* __restrict__ offs, int n) {
  __shared__ int sd[512];
  int t = threadIdx.x;
  int i = blockIdx.x * 512 + t;
  int v = (i < n) ? counts[i] : 0;
  sd[t] = v;
  __syncthreads();
  for (int off = 1; off < 512; off <<= 1) {
    int x = (t >= off) ? sd[t - off] : 0;
    __syncthreads();
    sd[t] += x;
    __syncthreads();
  }
  if (i < n) offs[i] = bsum[blockIdx.x] + sd[t] - v;
}

// ---------------- ATOMIC-FREE CSR: MSD 2-level counting sort ----------------
__global__ __launch_bounds__(256) void k_p1count(
    const int* __restrict__ dst, int* __restrict__ histT,
    int ne, int chunk, int G, int nbin) {
  __shared__ int hist[512];
  int g = blockIdx.x, t = threadIdx.x;
  for (int i = t; i < nbin; i += 256) hist[i] = 0;
  __syncthreads();
  int e0 = g * chunk, e1 = e0 + chunk; if (e1 > ne) e1 = ne;
  for (int e = e0 + t; e < e1; e += 256) atomicAdd(&hist[dst[e] >> 8], 1);
  __syncthreads();
  for (int i = t; i < nbin; i += 256) histT[i * G + g] = hist[i];
}

__global__ __launch_bounds__(256) void k_p1scat(
    const int* __restrict__ src, const int* __restrict__ dst,
    const float* __restrict__ ea, const int* __restrict__ histS,
    const float* __restrict__ We1, const float* __restrict__ ae1,
    const float* __restrict__ We2, const float* __restrict__ ae2,
    uint2* __restrict__ tmpR, int ne, int chunk, int G, int nbin) {
  __shared__ int cur[512];
  int g = blockIdx.x, t = threadIdx.x;
  for (int i = t; i < nbin; i += 256) cur[i] = histS[i * G + g];
  float w01 = 0.f, w11 = 0.f, w02 = 0.f, w12 = 0.f;
  #pragma unroll
  for (int c = 0; c < C; ++c) {
    w01 += We1[c] * ae1[c]; w11 += We1[C + c] * ae1[c];
    w02 += We2[c] * ae2[c]; w12 += We2[C + c] * ae2[c];
  }
  __syncthreads();
  int e0 = g * chunk, e1 = e0 + chunk; if (e1 > ne) e1 = ne;
  for (int e = e0 + t; e < e1; e += 256) {
    int d = dst[e];
    int pos = atomicAdd(&cur[d >> 8], 1);   // LDS atomic
    u32x2 ab = __builtin_nontemporal_load((const u32x2*)(ea + 2 * (size_t)e));
    float ax = __uint_as_float(ab.x);
    float ay = __uint_as_float(ab.y);
    __half2 hp = __floats2half2_rn(ax * w01 + ay * w11, ax * w02 + ay * w12);
    unsigned hb;
    memcpy(&hb, &hp, 4);
    // pack: word0 = src (bits 0..23) | fine-bin (bits 24..31)
    tmpR[pos] = make_uint2((unsigned)src[e] | ((unsigned)(d & 255) << 24), hb);
  }
}

// p2 + FUSED layer-1 gather. After the scatter pass this block's bucket slice
// [cs0,cs1) is L2-resident; thread t owns node b*256+t, with o0=cs0+excl and
// count v from the fine histogram (no offs re-read). Eliminates the separate
// layer-1 k_gather dispatch and its cold 25.6MB bucket re-read.
__global__ __launch_bounds__(256) void k_p2g(
    const uint2* __restrict__ tmpR, const int* __restrict__ histS,
    uint2* __restrict__ bucket, int* __restrict__ offs,
    const float* __restrict__ a_s, const float* __restrict__ a_d,
    const __half* __restrict__ hh, const float* __restrict__ bias,
    float* __restrict__ outv, float* __restrict__ bnsum, float* __restrict__ bnsq,
    int G, int nbin, int n, int ne) {
  __shared__ int hist[256], scn[256], cur[256];
  __shared__ float sbn[32];
  int b = blockIdx.x, t = threadIdx.x;
  int cs0 = histS[b * G];
  int cs1 = (b + 1 < nbin) ? histS[(b + 1) * G] : ne;
  hist[t] = 0;
  if (t < 32) sbn[t] = 0.f;
  __syncthreads();
  for (int i = cs0 + t; i < cs1; i += 256) {
    u32x2 r = __builtin_nontemporal_load((const u32x2*)(tmpR + i));
    atomicAdd(&hist[r.x >> 24], 1);
  }
  __syncthreads();
  int cnt = hist[t];
  scn[t] = cnt;
  __syncthreads();
  for (int off = 1; off < 256; off <<= 1) {
    int x = (t >= off) ? scn[t - off] : 0;
    __syncthreads();
    scn[t] += x;
    __syncthreads();
  }
  int excl = scn[t] - cnt;
  int node = b * 256 + t;
  if (node <= n) offs[node] = cs0 + excl;
  if (b == 0 && t == 0) offs[n] = ne;
  cur[t] = cs0 + excl;
  __syncthreads();
  for (int i = cs0 + t; i < cs1; i += 256) {
    u32x2 r = __builtin_nontemporal_load((const u32x2*)(tmpR + i));
    int pos = atomicAdd(&cur[r.x >> 24], 1);  // LDS atomic
    bucket[pos] = make_uint2(r.x & 0x00FFFFFFu, r.y);
  }
  __threadfence();
  __syncthreads();

  // ---- fused layer-1 gather: thread t = node, edges [o0, o0+cnt) L2-hot ----
  float vout[C];
  #pragma unroll
  for (int j = 0; j < C; ++j) vout[j] = 0.f;
  if (node < n) {
    int o0 = cs0 + excl, o1 = o0 + cnt;
    float adi = a_d[node], asi = a_s[node];
    float acc[C];
    #pragma unroll
    for (int j = 0; j < C; ++j) acc[j] = 0.f;
    float den = 0.f, ssum = 0.f;
    for (int e = o0; e < o1; ++e) {
      uint2 rec = bucket[e];
      int s = (int)rec.x;
      unsigned scb = rec.y;
      __half2 sc2;
      memcpy(&sc2, &scb, 4);
      float se = __low2float(sc2);
      float asv = a_s[s];
      const uint4* hp = (const uint4*)(hh + ((size_t)s << 4));
      uint4 h0 = hp[0], h1 = hp[1];
      float lg = asv + adi + se;
      lg = lg > 0.f ? lg : 0.2f * lg;
      float ex = __expf(lg);
      den += ex; ssum += se;
      __half2 q0, q1, q2, q3, q4, q5, q6, q7;
      memcpy(&q0, &h0.x, 4); memcpy(&q1, &h0.y, 4);
      memcpy(&q2, &h0.z, 4); memcpy(&q3, &h0.w, 4);
      memcpy(&q4, &h1.x, 4); memcpy(&q5, &h1.y, 4);
      memcpy(&q6, &h1.z, 4); memcpy(&q7, &h1.w, 4);
      float2 g0 = __half22float2(q0), g1 = __half22float2(q1);
      float2 g2 = __half22float2(q2), g3 = __half22float2(q3);
      float2 g4 = __half22float2(q4), g5 = __half22float2(q5);
      float2 g6 = __half22float2(q6), g7 = __half22float2(q7);
      acc[0] += ex * g0.x;  acc[1] += ex * g0.y;
      acc[2] += ex * g1.x;  acc[3] += ex * g1.y;
      acc[4] += ex * g2.x;  acc[5] += ex * g2.y;
      acc[6] += ex * g3.x;  acc[7] += ex * g3.y;
      acc[8] += ex * g4.x;  acc[9] += ex * g4.y;
      acc[10] += ex * g5.x; acc[11] += ex * g5.y;
      acc[12] += ex * g6.x; acc[13] += ex * g6.y;
      acc[14] += ex * g7.x; acc[15] += ex * g7.y;
    }
    // self loop (mean edge-attr term is linear in the precomputed scalar)
    float dgc = fmaxf((float)cnt, 1.f);
    float lg = asi + adi + ssum / dgc;
    lg = lg > 0.f ? lg : 0.2f * lg;
    float exs = __expf(lg);
    const uint4* hp = (const uint4*)(hh + ((size_t)node << 4));
    uint4 h0 = hp[0], h1 = hp[1];
    __half2 q0, q1, q2, q3, q4, q5, q6, q7;
    memcpy(&q0, &h0.x, 4); memcpy(&q1, &h0.y, 4);
    memcpy(&q2, &h0.z, 4); memcpy(&q3, &h0.w, 4);
    memcpy(&q4, &h1.x, 4); memcpy(&q5, &h1.y, 4);
    memcpy(&q6, &h1.z, 4); memcpy(&q7, &h1.w, 4);
    float hs[C] = {
      __low2float(q0), __high2float(q0), __low2float(q1), __high2float(q1),
      __low2float(q2), __high2float(q2), __low2float(q3), __high2float(q3),
      __low2float(q4), __high2float(q4), __low2float(q5), __high2float(q5),
      __low2float(q6), __high2float(q6), __low2float(q7), __high2float(q7)};
    float inv = 1.f / (den + exs);
    #pragma unroll
    for (int j = 0; j < C; ++j)
      vout[j] = fmaxf((acc[j] + exs * hs[j]) * inv + bias[j], 0.f);
    float* op = outv + ((size_t)node << 4);
    #pragma unroll
    for (int j = 0; j < 4; ++j) {
      f32x4 wv = {vout[4 * j], vout[4 * j + 1], vout[4 * j + 2], vout[4 * j + 3]};
      __builtin_nontemporal_store(wv, (f32x4*)(op + 4 * j));
    }
  }

  // ---- BN stats (mean over all n nodes; inactive threads contribute 0) ----
  #pragma unroll
  for (int j = 0; j < C; ++j) {
    float s = vout[j], q = vout[j] * vout[j];
    for (int o = 32; o > 0; o >>= 1) { s += __shfl_down(s, o); q += __shfl_down(q, o); }
    if ((t & 63) == 0) { atomicAdd(&sbn[j], s); atomicAdd(&sbn[16 + j], q); }
  }
  __syncthreads();
  if (t < 16) atomicAdd(&bnsum[t], sbn[t]);
  else if (t < 32) atomicAdd(&bnsq[t - 16], sbn[t]);
}

// ---------------- FALLBACK CSR (atomic path) ----------------
__global__ __launch_bounds__(256) void k_hist_rank(
    const int* __restrict__ dst, int* __restrict__ counts,
    int* __restrict__ rank, int ne) {
  int e = blockIdx.x * 256 + threadIdx.x;
  if (e < ne) rank[e] = atomicAdd(&counts[dst[e]], 1);
}

__global__ __launch_bounds__(256) void k_scatter(
    const int* __restrict__ src, const int* __restrict__ dst,
    const float2* __restrict__ ea, const int* __restrict__ offs,
    const int* __restrict__ rank,
    const float* __restrict__ We1, const float* __restrict__ ae1,
    const float* __restrict__ We2, const float* __restrict__ ae2,
    uint2* __restrict__ bucket, int ne) {
  int e = blockIdx.x * 256 + threadIdx.x;
  if (e >= ne) return;
  float w01 = 0.f, w11 = 0.f, w02 = 0.f, w12 = 0.f;
  #pragma unroll
  for (int c = 0; c < C; ++c) {
    w01 += We1[c] * ae1[c]; w11 += We1[C + c] * ae1[c];
    w02 += We2[c] * ae2[c]; w12 += We2[C + c] * ae2[c];
  }
  int d = dst[e];
  float2 a = ea[e];
  __half2 hp = __floats2half2_rn(a.x * w01 + a.y * w11, a.x * w02 + a.y * w12);
  unsigned hb;
  memcpy(&hb, &hp, 4);
  bucket[offs[d] + rank[e]] = make_uint2((unsigned)src[e], hb);
}

// ---------------- per-node gather: 4 lanes per node, 2 lanes per edge -------
__global__ __launch_bounds__(256) void k_gather(
    const uint2* __restrict__ bucket, const int* __restrict__ offs,
    const float* __restrict__ a_s, const float* __restrict__ a_d,
    const __half* __restrict__ hh, const float* __restrict__ bias,
    float* __restrict__ outv, float* __restrict__ bnsum, float* __restrict__ bnsq,
    int lay, int do_bn, int n) {
  __shared__ float sbn[32];
  int t = threadIdx.x;
  if (do_bn) {
    if (t < 32) sbn[t] = 0.f;
    __syncthreads();
  }

  int node = blockIdx.x * 64 + (t >> 2);
  int l = t & 3, f = l & 1, p = l >> 1;   // 2 pairs per node

  float acc[8];
  #pragma unroll
  for (int j = 0; j < 8; ++j) acc[j] = 0.f;
  float den = 0.f, ssum = 0.f;
  int o0 = 0, o1 = 0;
  float adi = 0.f, asi = 0.f;
  if (node < n) {
    o0 = offs[node]; o1 = offs[node + 1];
    adi = a_d[node]; asi = a_s[node];
    int e = o0 + p;
    u32x2 r = {0u, 0u};
    if (e < o1) r = __builtin_nontemporal_load((const u32x2*)(bucket + e));
    while (e < o1) {
      int en = e + 2;
      u32x2 rn = {0u, 0u};
      if (en < o1) rn = __builtin_nontemporal_load((const u32x2*)(bucket + en));
      int s = (int)r.x;
      unsigned scb = r.y;
      __half2 sc2;
      memcpy(&sc2, &scb, 4);
      float se = lay ? __high2float(sc2) : __low2float(sc2);
      float asv = a_s[s];
      uint4 hv = *(const uint4*)(hh + ((size_t)s << 4) + (f << 3));
      float lg = asv + adi + se;
      lg = lg > 0.f ? lg : 0.2f * lg;
      float ex = __expf(lg);
      den += ex; ssum += se;
      __half2 t0, t1, t2, t3;
      memcpy(&t0, &hv.x, 4); memcpy(&t1, &hv.y, 4);
      memcpy(&t2, &hv.z, 4); memcpy(&t3, &hv.w, 4);
      float2 g0 = __half22float2(t0), g1 = __half22float2(t1);
      float2 g2 = __half22float2(t2), g3 = __half22float2(t3);
      acc[0] += ex * g0.x; acc[1] += ex * g0.y;
      acc[2] += ex * g1.x; acc[3] += ex * g1.y;
      acc[4] += ex * g2.x; acc[5] += ex * g2.y;
      acc[6] += ex * g3.x; acc[7] += ex * g3.y;
      r = rn; e = en;
    }
  }
  den += __shfl_xor(den, 2);
  ssum += __shfl_xor(ssum, 2);
  #pragma unroll
  for (int j = 0; j < 8; ++j) acc[j] += __shfl_xor(acc[j], 2);

  float v[8];
  #pragma unroll
  for (int j = 0; j < 8; ++j) v[j] = 0.f;
  if (node < n) {
    float dgc = fmaxf((float)(o1 - o0), 1.f);
    float lg = asi + adi + ssum / dgc;
    lg = lg > 0.f ? lg : 0.2f * lg;
    float exs = __expf(lg);
    uint4 hv = *(const uint4*)(hh + ((size_t)node << 4) + (f << 3));
    __half2 t0, t1, t2, t3;
    memcpy(&t0, &hv.x, 4); memcpy(&t1, &hv.y, 4);
    memcpy(&t2, &hv.z, 4); memcpy(&t3, &hv.w, 4);
    float2 g0 = __half22float2(t0), g1 = __half22float2(t1);
    float2 g2 = __half22float2(t2), g3 = __half22float2(t3);
    float hs[8] = {g0.x, g0.y, g1.x, g1.y, g2.x, g2.y, g3.x, g3.y};
    float inv = 1.f / (den + exs);
    const float* bp = bias + f * 8;
    #pragma unroll
    for (int j = 0; j < 8; ++j)
      v[j] = fmaxf((acc[j] + exs * hs[j]) * inv + bp[j], 0.f);
    if (p == 0) {
      f32x4 w0 = {v[0], v[1], v[2], v[3]};
      f32x4 w1 = {v[4], v[5], v[6], v[7]};
      float* op = outv + ((size_t)node << 4) + f * 8;
      __builtin_nontemporal_store(w0, (f32x4*)op);
      __builtin_nontemporal_store(w1, (f32x4*)(op + 4));
    }
  }

  if (do_bn) {
    float sv[8], qv[8];
    bool act = (node < n) && (p == 0);
    #pragma unroll
    for (int j = 0; j < 8; ++j) {
      sv[j] = act ? v[j] : 0.f;
      qv[j] = sv[j] * sv[j];
    }
    #pragma unroll
    for (int j = 0; j < 8; ++j) {
      sv[j] += __shfl_down(sv[j], 4);  qv[j] += __shfl_down(qv[j], 4);
      sv[j] += __shfl_down(sv[j], 8);  qv[j] += __shfl_down(qv[j], 8);
      sv[j] += __shfl_down(sv[j], 16); qv[j] += __shfl_down(qv[j], 16);
      sv[j] += __shfl_down(sv[j], 32); qv[j] += __shfl_down(qv[j], 32);
    }
    if ((t & 63) < 2) {
      #pragma unroll
      for (int j = 0; j < 8; ++j) {
        atomicAdd(&sbn[f * 8 + j], sv[j]);
        atomicAdd(&sbn[16 + f * 8 + j], qv[j]);
      }
    }
    __syncthreads();
    if (t < 16) atomicAdd(&bnsum[t], sbn[t]);
    else if (t < 32) atomicAdd(&bnsq[t - 16], sbn[t]);
  }
}

__global__ void k_bnp(const float* __restrict__ bnsum, const float* __restrict__ bnsq,
                      const float* __restrict__ g, const float* __restrict__ bb,
                      float* __restrict__ scale, float* __restrict__ shift, float invn) {
  int c = threadIdx.x;
  if (c >= C) return;
  float mean = bnsum[c] * invn;
  float var = bnsq[c] * invn - mean * mean;
  float s = g[c] * rsqrtf(var + 1e-5f);
  scale[c] = s; shift[c] = bb[c] - mean * s;
}

// ---------------- BN + 16x16 matmul + a_s/a_d for layer 2 ----------------
__global__ __launch_bounds__(256) void k_node2(
    const float* __restrict__ outv, const float* __restrict__ scale,
    const float* __restrict__ shift, const float* __restrict__ W2,
    const float* __restrict__ asw, const float* __restrict__ adw,
    __half* __restrict__ hh, float* __restrict__ a_s, float* __restrict__ a_d, int n) {
  __shared__ float w2s[C * C];
  if (threadIdx.x < C * C) w2s[threadIdx.x] = W2[threadIdx.x];
  __syncthreads();
  int i = blockIdx.x * 256 + threadIdx.x;
  if (i >= n) return;
  float hn[C];
  #pragma unroll
  for (int c = 0; c < C; ++c) hn[c] = outv[(size_t)i * C + c] * scale[c] + shift[c];
  float h2[C];
  #pragma unroll
  for (int j = 0; j < C; ++j) {
    float acc = 0.f;
    #pragma unroll
    for (int c = 0; c < C; ++c) acc += hn[c] * w2s[c * C + j];
    h2[j] = acc;
  }
  float hs = 0.f, hd = 0.f;
  #pragma unroll
  for (int j = 0; j < C; ++j) { hs += h2[j] * asw[j]; hd += h2[j] * adw[j]; }
  a_s[i] = hs; a_d[i] = hd;
  unsigned wbits[8];
  #pragma unroll
  for (int j = 0; j < 8; ++j) {
    __half2 hq = __floats2half2_rn(h2[2 * j], h2[2 * j + 1]);
    memcpy(&wbits[j], &hq, 4);
  }
  uint4* hp = (uint4*)(hh + (size_t)i * 16);
  hp[0] = make_uint4(wbits[0], wbits[1], wbits[2], wbits[3]);
  hp[1] = make_uint4(wbits[4], wbits[5], wbits[6], wbits[7]);
}

// ---------------- graph segment offsets ----------------
__global__ void k_gstart(const int* __restrict__ batch, int* __restrict__ gs,
                         int n, int B_) {
  int g = blockIdx.x * blockDim.x + threadIdx.x;
  if (g > B_) return;
  if (g == B_) { gs[B_] = n; return; }
  int lo = 0, hi = n;
  while (lo < hi) { int mid = (lo + hi) >> 1; if (batch[mid] < g) lo = mid + 1; else hi = mid; }
  gs[g] = lo;
}

__global__ __launch_bounds__(256) void k_xe(
    const float* __restrict__ outv, const int* __restrict__ gs,
    float* __restrict__ xe, int B_) {
  int wave = blockIdx.x * 4 + (threadIdx.x >> 6);
  if (wave >= B_) return;
  int lane = threadIdx.x & 63;
  int c = lane & 15, sub = lane >> 4;
  int base = gs[wave], end = gs[wave + 1];
  float s = 0.f;
  for (int n0 = base + sub; n0 < end; n0 += 4) s += outv[(size_t)n0 * C + c];
  s += __shfl_down(s, 32);
  s += __shfl_down(s, 16);
  if (lane < 16) xe[(size_t)wave * C + c] = s / fmaxf((float)(end - base), 1.f);
}

// ---------------- D2RL tail ----------------
__global__ __launch_bounds__(512) void k_tail_z3(
    const float* __restrict__ xe_in,
    const float* __restrict__ gL1, const float* __restrict__ bL1,
    const float* __restrict__ Wl1, const float* __restrict__ bl1,
    const float* __restrict__ gL2, const float* __restrict__ bL2,
    const float* __restrict__ Wl2, const float* __restrict__ bl2,
    const float* __restrict__ gL3, const float* __restrict__ bL3,
    const float* __restrict__ Wl3, const float* __restrict__ bl3,
    float* __restrict__ z3buf, int B_) {
  __shared__ float ssum[2 * C], ssq[2 * C], sc[2 * C], sh[2 * C];
  int t = threadIdx.x;
  float invB = 1.f / (float)B_;
  float xe[C];
  #pragma unroll
  for (int c = 0; c < C; ++c) xe[c] = xe_in[(size_t)t * C + c];

  if (t < 2 * C) { ssum[t] = 0.f; ssq[t] = 0.f; }
  __syncthreads();
  #pragma unroll
  for (int c = 0; c < C; ++c) {
    float s = xe[c], q = xe[c] * xe[c];
    for (int o = 32; o > 0; o >>= 1) { s += __shfl_down(s, o); q += __shfl_down(q, o); }
    if ((t & 63) == 0) { atomicAdd(&ssum[c], s); atomicAdd(&ssq[c], q); }
  }
  __syncthreads();
  if (t < C) {
    float mean = ssum[t] * invB, var = ssq[t] * invB - mean * mean;
    float s = gL1[t] * rsqrtf(var + 1e-5f);
    sc[t] = s; sh[t] = bL1[t] - mean * s;
  }
  __syncthreads();
  float z[C];
  #pragma unroll
  for (int j = 0; j < C; ++j) {
    float acc = bl1[j];
    #pragma unroll
    for (int c = 0; c < C; ++c) acc += (xe[c] * sc[c] + sh[c]) * Wl1[c * C + j];
    z[j] = fmaxf(acc, 0.f);
  }
  __syncthreads();

  if (t < 2 * C) { ssum[t] = 0.f; ssq[t] = 0.f; }
  __syncthreads();
  #pragma unroll
  for (int c = 0; c < C; ++c) {
    float s = z[c], q = z[c] * z[c];
    for (int o = 32; o > 0; o >>= 1) { s += __shfl_down(s, o); q += __shfl_down(q, o); }
    if ((t & 63) == 0) { atomicAdd(&ssum[c], s); atomicAdd(&ssq[c], q); }
    float s2 = xe[c], q2 = xe[c] * xe[c];
    for (int o = 32; o > 0; o >>= 1) { s2 += __shfl_down(s2, o); q2 += __shfl_down(q2, o); }
    if ((t & 63) == 0) { atomicAdd(&ssum[C + c], s2); atomicAdd(&ssq[C + c], q2); }
  }
  __syncthreads();
  if (t < 2 * C) {
    float mean = ssum[t] * invB, var = ssq[t] * invB - mean * mean;
    float s = gL2[t] * rsqrtf(var + 1e-5f);
    sc[t] = s; sh[t] = bL2[t] - mean * s;
  }
  __syncthreads();
  float z2[C];
  #pragma unroll
  for (int j = 0; j < C; ++j) {
    float acc = bl2[j];
    #pragma unroll
    for (int c = 0; c < C; ++c) acc += (z[c] * sc[c] + sh[c]) * Wl2[c * C + j];
    #pragma unroll
    for (int c = 0; c < C; ++c) acc += (xe[c] * sc[C + c] + sh[C + c]) * Wl2[(C + c) * C + j];
    z2[j] = fmaxf(acc, 0.f);
  }
  __syncthreads();

  if (t < 2 * C) { ssum[t] = 0.f; ssq[t] = 0.f; }
  __syncthreads();
  #pragma unroll
  for (int c = 0; c < C; ++c) {
    float s = z2[c], q = z2[c] * z2[c];
    for (int o = 32; o > 0; o >>= 1) { s += __shfl_down(s, o); q += __shfl_down(q, o); }
    if ((t & 63) == 0) { atomicAdd(&ssum[c], s); atomicAdd(&ssq[c], q); }
    float s2 = xe[c], q2 = xe[c] * xe[c];
    for (int o = 32; o > 0; o >>= 1) { s2 += __shfl_down(s2, o); q2 += __shfl_down(q2, o); }
    if ((t & 63) == 0) { atomicAdd(&ssum[C + c], s2); atomicAdd(&ssq[C + c], q2); }
  }
  __syncthreads();
  if (t < 2 * C) {
    float mean = ssum[t] * invB, var = ssq[t] * invB - mean * mean;
    float s = gL3[t] * rsqrtf(var + 1e-5f);
    sc[t] = s; sh[t] = bL3[t] - mean * s;
  }
  __syncthreads();
  #pragma unroll
  for (int j = 0; j < C; ++j) {
    float acc = bl3[j];
    #pragma unroll
    for (int c = 0; c < C; ++c) acc += (z2[c] * sc[c] + sh[c]) * Wl3[c * C + j];
    #pragma unroll
    for (int c = 0; c < C; ++c) acc += (xe[c] * sc[C + c] + sh[C + c]) * Wl3[(C + c) * C + j];
    z3buf[(size_t)t * C + j] = fmaxf(acc, 0.f);
  }
}

// ---------------- heads ----------------
__global__ __launch_bounds__(256) void k_heads(
    const float* __restrict__ z3buf,
    const float* __restrict__ Wx, const float* __restrict__ bx,
    const float* __restrict__ Wy, const float* __restrict__ by,
    const float* __restrict__ Wr, const float* __restrict__ br,
    float* __restrict__ out, int B_) {
  int wv = blockIdx.x * 4 + (threadIdx.x >> 6);
  if (wv >= B_) return;
  int lane = threadIdx.x & 63;
  float z[C];
  #pragma unroll
  for (int c = 0; c < C; ++c) z[c] = z3buf[(size_t)wv * C + c];

  float ax = bx[lane];
  #pragma unroll
  for (int c = 0; c < C; ++c) ax += z[c] * Wx[c * 64 + lane];
  float m = ax;
  #pragma unroll
  for (int o = 32; o > 0; o >>= 1) m = fmaxf(m, __shfl_xor(m, o));
  float e = __expf(ax - m);
  float s = e;
  #pragma unroll
  for (int o = 32; o > 0; o >>= 1) s += __shfl_xor(s, o);
  out[(size_t)wv * 64 + lane] = e / s;

  float ay = by[lane];
  #pragma unroll
  for (int c = 0; c < C; ++c) ay += z[c] * Wy[c * 64 + lane];
  m = ay;
  #pragma unroll
  for (int o = 32; o > 0; o >>= 1) m = fmaxf(m, __shfl_xor(m, o));
  e = __expf(ay - m);
  s = e;
  #pragma unroll
  for (int o = 32; o > 0; o >>= 1) s += __shfl_xor(s, o);
  out[(size_t)B_ * 64 + (size_t)wv * 64 + lane] = e / s;

  if (lane < 4) {
    float ar = br[lane];
    #pragma unroll
    for (int c = 0; c < C; ++c) ar += z[c] * Wr[c * 4 + lane];
    float mr = ar;
    mr = fmaxf(mr, __shfl_xor(mr, 1));
    mr = fmaxf(mr, __shfl_xor(mr, 2));
    float er = __expf(ar - mr);
    float sr = er;
    sr += __shfl_xor(sr, 1);
    sr += __shfl_xor(sr, 2);
    out[(size_t)B_ * 128 + (size_t)wv * 4 + lane] = er / sr;
  }
}

extern "C" void kernel_launch(void* const* d_in, const int* in_sizes, int n_in,
                              void* d_out, int out_size, void* d_ws, size_t ws_size,
                              hipStream_t stream) {
  const float* x     = (const float*)d_in[0];
  const int*   eidx  = (const int*)d_in[1];
  const float* eattr = (const float*)d_in[2];
  const int*   batch = (const int*)d_in[3];
  const float* W1  = (const float*)d_in[4];
  const float* We1 = (const float*)d_in[5];
  const float* as1 = (const float*)d_in[6];
  const float* ad1 = (const float*)d_in[7];
  const float* ae1 = (const float*)d_in[8];
  const float* b1  = (const float*)d_in[9];
  const float* g1  = (const float*)d_in[10];
  const float* bb1 = (const float*)d_in[11];
  const float* W2  = (const float*)d_in[12];
  const float* We2 = (const float*)d_in[13];
  const float* as2 = (const float*)d_in[14];
  const float* ad2 = (const float*)d_in[15];
  const float* ae2 = (const float*)d_in[16];
  const float* b2  = (const float*)d_in[17];
  const float* gL1 = (const float*)d_in[18];
  const float* bL1 = (const float*)d_in[19];
  const float* Wl1 = (const float*)d_in[20];
  const float* bl1 = (const float*)d_in[21];
  const float* gL2 = (const float*)d_in[22];
  const float* bL2 = (const float*)d_in[23];
  const float* Wl2 = (const float*)d_in[24];
  const float* bl2 = (const float*)d_in[25];
  const float* gL3 = (const float*)d_in[26];
  const float* bL3 = (const float*)d_in[27];
  const float* Wl3 = (const float*)d_in[28];
  const float* bl3 = (const float*)d_in[29];
  const float* Wx  = (const float*)d_in[30];
  const float* bx  = (const float*)d_in[31];
  const float* Wy  = (const float*)d_in[32];
  const float* by  = (const float*)d_in[33];
  const float* Wr  = (const float*)d_in[34];
  const float* br  = (const float*)d_in[35];

  int N = in_sizes[3];
  int E = in_sizes[2] / 2;
  int B = out_size / 132;

  const int* src = eidx;
  const int* dst = eidx + E;

  const int G = 128;                       // partition blocks (L2 write-set fit)
  int nbin = (N + 255) >> 8;               // coarse bins (dst>>8)
  int nscan = nbin * G;
  int chunk = (E + G - 1) / G;
  int nblk2 = (nscan + 511) / 512;

  // ---- layout ----
  char* w = (char*)d_ws;
  size_t o = 0;
  auto alloc = [&](size_t bytes) { char* p = w + o; o += (bytes + 15) & ~15ull; return p; };
  uint2*  bucket = (uint2*)alloc((size_t)E * 8);
  uint2*  tmpR   = (uint2*)alloc((size_t)E * 8);
  __half* hh     = (__half*)alloc((size_t)N * C * 2);
  float*  outv   = (float*)alloc((size_t)N * C * 4);
  float*  a_s    = (float*)alloc((size_t)N * 4);
  float*  a_d    = (float*)alloc((size_t)N * 4);
  int*    counts = (int*)alloc((size_t)(N + 4) * 4);
  int*    offs   = (int*)alloc((size_t)(N + 4) * 4);
  int*    histT  = (int*)alloc((size_t)(nscan + 4) * 4);
  int*    histS  = (int*)alloc((size_t)(nscan + 4) * 4);
  int*    bsum   = (int*)alloc((size_t)(nblk2 + 516) * 4);
  float*  bn     = (float*)alloc(64 * 4);
  float*  xe     = (float*)alloc((size_t)B * C * 4);
  int*    gs     = (int*)alloc((size_t)(B + 4) * 4);
  float*  z3buf  = (float*)alloc((size_t)B * C * 4);
  size_t need = o;

  // radix requires src < 2^24 for the packed record
  bool radix = (need <= ws_size) && (nbin <= 512) && (nblk2 <= 512) && (N <= (1 << 24));

  hipMemsetAsync(bn, 0, 32 * 4, stream);
  k_gemm1<<<(N + 63) / 64, 256, 0, stream>>>(x, W1, as1, ad1, hh, a_s, a_d, N);

  if (radix) {
    k_p1count<<<G, 256, 0, stream>>>(dst, histT, E, chunk, G, nbin);
    k_scan1<<<nblk2, 512, 0, stream>>>(histT, bsum, nscan);
    k_scan2<<<1, 512, 0, stream>>>(bsum, histS, nblk2, nscan);
    k_scan3<<<nblk2, 512, 0, stream>>>(histT, bsum, histS, nscan);
    k_p1scat<<<G, 256, 0, stream>>>(src, dst, eattr, histS,
                                    We1, ae1, We2, ae2, tmpR, E, chunk, G, nbin);
    // p2 + fused layer-1 gather (+BN stats)
    k_p2g<<<nbin, 256, 0, stream>>>(tmpR, histS, bucket, offs,
                                    a_s, a_d, hh, b1, outv, bn, bn + 16,
                                    G, nbin, N, E);
  } else {
    int* rank = (int*)tmpR;
    int nblk = (N + 511) / 512;
    int ebl = (E + 255) / 256;
    hipMemsetAsync(counts, 0, (size_t)N * 4, stream);
    k_hist_rank<<<ebl, 256, 0, stream>>>(dst, counts, rank, E);
    k_scan1<<<nblk, 512, 0, stream>>>(counts, bsum, N);
    k_scan2<<<1, 512, 0, stream>>>(bsum, offs, nblk, N);
    k_scan3<<<nblk, 512, 0, stream>>>(counts, bsum, offs, N);
    k_scatter<<<ebl, 256, 0, stream>>>(src, dst, (const float2*)eattr, offs, rank,
                                       We1, ae1, We2, ae2, bucket, E);
    k_gather<<<(N + 63) / 64, 256, 0, stream>>>(bucket, offs, a_s, a_d, hh, b1,
                                                outv, bn, bn + 16, 0, 1, N);
  }

  int nbl = (N + 255) / 256;
  k_bnp<<<1, 64, 0, stream>>>(bn, bn + 16, g1, bb1, bn + 32, bn + 48, 1.f / (float)N);
  k_node2<<<nbl, 256, 0, stream>>>(outv, bn + 32, bn + 48, W2, as2, ad2, hh, a_s, a_d, N);
  k_gather<<<(N + 63) / 64, 256, 0, stream>>>(bucket, offs, a_s, a_d, hh, b2,
                                              outv, bn, bn + 16, 1, 0, N);
  k_gstart<<<(B + 1 + 255) / 256, 256, 0, stream>>>(batch, gs, N, B);
  k_xe<<<(B + 3) / 4, 256, 0, stream>>>(outv, gs, xe, B);
  k_tail_z3<<<1, B, 0, stream>>>(xe, gL1, bL1, Wl1, bl1, gL2, bL2, Wl2, bl2,
                                 gL3, bL3, Wl3, bl3, z3buf, B);
  k_heads<<<(B + 3) / 4, 256, 0, stream>>>(z3buf, Wx, bx, Wy, by, Wr, br,
                                           (float*)d_out, B);
}

// Round 12
// 684.708 us; speedup vs baseline: 1.0808x; 1.0808x over previous
//
#include <hip/hip_runtime.h>
#include <hip/hip_fp16.h>
#include <math.h>

#define C 16
#define FIN 128

typedef unsigned int u32x2 __attribute__((ext_vector_type(2)));

// ---------------- GEMM x@W1 (100k x 128 x 16) + fused a_s/a_d ----------------
__global__ __launch_bounds__(256) void k_gemm1(
    const float* __restrict__ x, const float* __restrict__ W,
    const float* __restrict__ asw, const float* __restrict__ adw,
    __half* __restrict__ hh, float* __restrict__ a_s, float* __restrict__ a_d, int n) {
  __shared__ float xs[64 * 129];
  __shared__ float Ws[FIN * C];
  __shared__ float pAs[4][64], pAd[4][64];
  int t = threadIdx.x;
  int node0 = blockIdx.x * 64;
  for (int i = t; i < FIN * C; i += 256) Ws[i] = W[i];
  for (int i = t; i < 64 * FIN; i += 256) {
    int r = i >> 7, c = i & 127;
    int node = node0 + r;
    xs[r * 129 + c] = (node < n) ? x[(size_t)node * FIN + c] : 0.f;
  }
  __syncthreads();
  int nn = t & 63, cg = (t >> 6) * 4, grp = t >> 6;
  float a0 = 0.f, a1 = 0.f, a2 = 0.f, a3 = 0.f;
  const float* xr = &xs[nn * 129];
  #pragma unroll 8
  for (int k = 0; k < FIN; ++k) {
    float xv = xr[k];
    const float* wr = &Ws[k * C + cg];
    a0 += xv * wr[0]; a1 += xv * wr[1]; a2 += xv * wr[2]; a3 += xv * wr[3];
  }
  int node = node0 + nn;
  if (node < n) {
    __half2 p0 = __floats2half2_rn(a0, a1), p1 = __floats2half2_rn(a2, a3);
    unsigned u0, u1;
    memcpy(&u0, &p0, 4); memcpy(&u1, &p1, 4);
    *(uint2*)(hh + (size_t)node * 16 + cg) = make_uint2(u0, u1);
  }
  pAs[grp][nn] = a0 * asw[cg] + a1 * asw[cg + 1] + a2 * asw[cg + 2] + a3 * asw[cg + 3];
  pAd[grp][nn] = a0 * adw[cg] + a1 * adw[cg + 1] + a2 * adw[cg + 2] + a3 * adw[cg + 3];
  __syncthreads();
  if (t < 64 && node0 + t < n) {
    a_s[node0 + t] = pAs[0][t] + pAs[1][t] + pAs[2][t] + pAs[3][t];
    a_d[node0 + t] = pAd[0][t] + pAd[1][t] + pAd[2][t] + pAd[3][t];
  }
}

// ---------------- generic scan kernels ----------------
__global__ __launch_bounds__(512) void k_scan1(const int* __restrict__ counts,
                                               int* __restrict__ bsum, int n) {
  __shared__ int sd[512];
  int i = blockIdx.x * 512 + threadIdx.x;
  sd[threadIdx.x] = (i < n) ? counts[i] : 0;
  __syncthreads();
  for (int s = 256; s > 0; s >>= 1) {
    if (threadIdx.x < s) sd[threadIdx.x] += sd[threadIdx.x + s];
    __syncthreads();
  }
  if (threadIdx.x == 0) bsum[blockIdx.x] = sd[0];
}

__global__ __launch_bounds__(512) void k_scan2(int* __restrict__ bsum,
                                               int* __restrict__ offs,
                                               int nblk, int n) {
  __shared__ int sd[512];
  int t = threadIdx.x;
  int v = (t < nblk) ? bsum[t] : 0;
  sd[t] = v;
  __syncthreads();
  for (int off = 1; off < 512; off <<= 1) {
    int x = (t >= off) ? sd[t - off] : 0;
    __syncthreads();
    sd[t] += x;
    __syncthreads();
  }
  if (t < nblk) bsum[t] = sd[t] - v;
  if (t == nblk - 1) offs[n] = sd[t];
}

__global__ __launch_bounds__(512) void k_scan3(const int* __restrict__ counts,
                                               const int* __restrict__ bsum,
                                               int* __restrict__ offs, int n) {
  __shared__ int sd[512];
  int t = threadIdx.x;
  int i = blockIdx.x * 512 + t;
  int v = (i < n) ? counts[i] : 0;
  sd[t] = v;
  __syncthreads();
  for (int off = 1; off < 512; off <<= 1) {
    int x = (t >= off) ? sd[t - off] : 0;
    __syncthreads();
    sd[t] += x;
    __syncthreads();
  }
  if (i < n) offs[i] = bsum[blockIdx.x] + sd[t] - v;
}

// ---------------- ATOMIC-FREE CSR: MSD 2-level counting sort (r6 champion) --
__global__ __launch_bounds__(256) void k_p1count(
    const int* __restrict__ dst, int* __restrict__ histT,
    int ne, int chunk, int G, int nbin) {
  __shared__ int hist[512];
  int g = blockIdx.x, t = threadIdx.x;
  for (int i = t; i < nbin; i += 256) hist[i] = 0;
  __syncthreads();
  int e0 = g * chunk, e1 = e0 + chunk; if (e1 > ne) e1 = ne;
  for (int e = e0 + t; e < e1; e += 256) atomicAdd(&hist[dst[e] >> 8], 1);
  __syncthreads();
  for (int i = t; i < nbin; i += 256) histT[i * G + g] = hist[i];
}

__global__ __launch_bounds__(256) void k_p1scat(
    const int* __restrict__ src, const int* __restrict__ dst,
    const float2* __restrict__ ea, const int* __restrict__ histS,
    const float* __restrict__ We1, const float* __restrict__ ae1,
    const float* __restrict__ We2, const float* __restrict__ ae2,
    uint2* __restrict__ tmpR, int* __restrict__ tmpD,
    int ne, int chunk, int G, int nbin) {
  __shared__ int cur[512];
  int g = blockIdx.x, t = threadIdx.x;
  for (int i = t; i < nbin; i += 256) cur[i] = histS[i * G + g];
  float w01 = 0.f, w11 = 0.f, w02 = 0.f, w12 = 0.f;
  #pragma unroll
  for (int c = 0; c < C; ++c) {
    w01 += We1[c] * ae1[c]; w11 += We1[C + c] * ae1[c];
    w02 += We2[c] * ae2[c]; w12 += We2[C + c] * ae2[c];
  }
  __syncthreads();
  int e0 = g * chunk, e1 = e0 + chunk; if (e1 > ne) e1 = ne;
  for (int e = e0 + t; e < e1; e += 256) {
    int d = dst[e];
    int pos = atomicAdd(&cur[d >> 8], 1);   // LDS atomic
    float2 a = ea[e];
    __half2 hp = __floats2half2_rn(a.x * w01 + a.y * w11, a.x * w02 + a.y * w12);
    unsigned hb;
    memcpy(&hb, &hp, 4);
    tmpR[pos] = make_uint2((unsigned)src[e], hb);
    tmpD[pos] = d;
  }
}

__global__ __launch_bounds__(256) void k_p2(
    const uint2* __restrict__ tmpR, const int* __restrict__ tmpD,
    const int* __restrict__ histS,
    uint2* __restrict__ bucket, int* __restrict__ offs,
    int G, int nbin, int n, int ne) {
  __shared__ int hist[256], scn[256], cur[256];
  int b = blockIdx.x, t = threadIdx.x;
  int cs0 = histS[b * G];
  int cs1 = (b + 1 < nbin) ? histS[(b + 1) * G] : ne;
  hist[t] = 0;
  __syncthreads();
  for (int i = cs0 + t; i < cs1; i += 256) atomicAdd(&hist[tmpD[i] & 255], 1);
  __syncthreads();
  int v = hist[t];
  scn[t] = v;
  __syncthreads();
  for (int off = 1; off < 256; off <<= 1) {
    int x = (t >= off) ? scn[t - off] : 0;
    __syncthreads();
    scn[t] += x;
    __syncthreads();
  }
  int excl = scn[t] - v;
  int node = b * 256 + t;
  if (node <= n) offs[node] = cs0 + excl;
  if (b == 0 && t == 0) offs[n] = ne;
  cur[t] = cs0 + excl;
  __syncthreads();
  for (int i = cs0 + t; i < cs1; i += 256) {
    int d = tmpD[i];
    int pos = atomicAdd(&cur[d & 255], 1);  // LDS atomic
    bucket[pos] = tmpR[i];
  }
}

// ---------------- FALLBACK CSR (atomic path) ----------------
__global__ __launch_bounds__(256) void k_hist_rank(
    const int* __restrict__ dst, int* __restrict__ counts,
    int* __restrict__ rank, int ne) {
  int e = blockIdx.x * 256 + threadIdx.x;
  if (e < ne) rank[e] = atomicAdd(&counts[dst[e]], 1);
}

__global__ __launch_bounds__(256) void k_scatter(
    const int* __restrict__ src, const int* __restrict__ dst,
    const float2* __restrict__ ea, const int* __restrict__ offs,
    const int* __restrict__ rank,
    const float* __restrict__ We1, const float* __restrict__ ae1,
    const float* __restrict__ We2, const float* __restrict__ ae2,
    uint2* __restrict__ bucket, int ne) {
  int e = blockIdx.x * 256 + threadIdx.x;
  if (e >= ne) return;
  float w01 = 0.f, w11 = 0.f, w02 = 0.f, w12 = 0.f;
  #pragma unroll
  for (int c = 0; c < C; ++c) {
    w01 += We1[c] * ae1[c]; w11 += We1[C + c] * ae1[c];
    w02 += We2[c] * ae2[c]; w12 += We2[C + c] * ae2[c];
  }
  int d = dst[e];
  float2 a = ea[e];
  __half2 hp = __floats2half2_rn(a.x * w01 + a.y * w11, a.x * w02 + a.y * w12);
  unsigned hb;
  memcpy(&hb, &hp, 4);
  bucket[offs[d] + rank[e]] = make_uint2((unsigned)src[e], hb);
}

// ---------------- per-node gather: 4 lanes per node, 2 lanes per edge -------
__global__ __launch_bounds__(256) void k_gather(
    const uint2* __restrict__ bucket, const int* __restrict__ offs,
    const float* __restrict__ a_s, const float* __restrict__ a_d,
    const __half* __restrict__ hh, const float* __restrict__ bias,
    float* __restrict__ outv, float* __restrict__ bnsum, float* __restrict__ bnsq,
    int lay, int do_bn, int n) {
  __shared__ float sbn[32];
  int t = threadIdx.x;
  if (do_bn) {
    if (t < 32) sbn[t] = 0.f;
    __syncthreads();
  }

  int node = blockIdx.x * 64 + (t >> 2);
  int l = t & 3, f = l & 1, p = l >> 1;   // 2 pairs per node

  float acc[8];
  #pragma unroll
  for (int j = 0; j < 8; ++j) acc[j] = 0.f;
  float den = 0.f, ssum = 0.f;
  int o0 = 0, o1 = 0;
  float adi = 0.f, asi = 0.f;
  if (node < n) {
    o0 = offs[node]; o1 = offs[node + 1];
    adi = a_d[node]; asi = a_s[node];
    int e = o0 + p;
    u32x2 r = {0u, 0u};
    if (e < o1) r = __builtin_nontemporal_load((const u32x2*)(bucket + e));
    while (e < o1) {
      int en = e + 2;
      u32x2 rn = {0u, 0u};
      if (en < o1) rn = __builtin_nontemporal_load((const u32x2*)(bucket + en));
      int s = (int)r.x;
      unsigned scb = r.y;
      __half2 sc2;
      memcpy(&sc2, &scb, 4);
      float se = lay ? __high2float(sc2) : __low2float(sc2);
      float asv = a_s[s];
      uint4 hv = *(const uint4*)(hh + ((size_t)s << 4) + (f << 3));
      float lg = asv + adi + se;
      lg = lg > 0.f ? lg : 0.2f * lg;
      float ex = __expf(lg);
      den += ex; ssum += se;
      __half2 t0, t1, t2, t3;
      memcpy(&t0, &hv.x, 4); memcpy(&t1, &hv.y, 4);
      memcpy(&t2, &hv.z, 4); memcpy(&t3, &hv.w, 4);
      float2 g0 = __half22float2(t0), g1 = __half22float2(t1);
      float2 g2 = __half22float2(t2), g3 = __half22float2(t3);
      acc[0] += ex * g0.x; acc[1] += ex * g0.y;
      acc[2] += ex * g1.x; acc[3] += ex * g1.y;
      acc[4] += ex * g2.x; acc[5] += ex * g2.y;
      acc[6] += ex * g3.x; acc[7] += ex * g3.y;
      r = rn; e = en;
    }
  }
  den += __shfl_xor(den, 2);
  ssum += __shfl_xor(ssum, 2);
  #pragma unroll
  for (int j = 0; j < 8; ++j) acc[j] += __shfl_xor(acc[j], 2);

  float v[8];
  #pragma unroll
  for (int j = 0; j < 8; ++j) v[j] = 0.f;
  if (node < n) {
    float dgc = fmaxf((float)(o1 - o0), 1.f);
    float lg = asi + adi + ssum / dgc;
    lg = lg > 0.f ? lg : 0.2f * lg;
    float exs = __expf(lg);
    uint4 hv = *(const uint4*)(hh + ((size_t)node << 4) + (f << 3));
    __half2 t0, t1, t2, t3;
    memcpy(&t0, &hv.x, 4); memcpy(&t1, &hv.y, 4);
    memcpy(&t2, &hv.z, 4); memcpy(&t3, &hv.w, 4);
    float2 g0 = __half22float2(t0), g1 = __half22float2(t1);
    float2 g2 = __half22float2(t2), g3 = __half22float2(t3);
    float hs[8] = {g0.x, g0.y, g1.x, g1.y, g2.x, g2.y, g3.x, g3.y};
    float inv = 1.f / (den + exs);
    const float* bp = bias + f * 8;
    #pragma unroll
    for (int j = 0; j < 8; ++j)
      v[j] = fmaxf((acc[j] + exs * hs[j]) * inv + bp[j], 0.f);
    if (p == 0) {
      float4* op = (float4*)(outv + ((size_t)node << 4));
      op[f * 2]     = make_float4(v[0], v[1], v[2], v[3]);
      op[f * 2 + 1] = make_float4(v[4], v[5], v[6], v[7]);
    }
  }

  if (do_bn) {
    float sv[8], qv[8];
    bool act = (node < n) && (p == 0);
    #pragma unroll
    for (int j = 0; j < 8; ++j) {
      sv[j] = act ? v[j] : 0.f;
      qv[j] = sv[j] * sv[j];
    }
    #pragma unroll
    for (int j = 0; j < 8; ++j) {
      sv[j] += __shfl_down(sv[j], 4);  qv[j] += __shfl_down(qv[j], 4);
      sv[j] += __shfl_down(sv[j], 8);  qv[j] += __shfl_down(qv[j], 8);
      sv[j] += __shfl_down(sv[j], 16); qv[j] += __shfl_down(qv[j], 16);
      sv[j] += __shfl_down(sv[j], 32); qv[j] += __shfl_down(qv[j], 32);
    }
    if ((t & 63) < 2) {
      #pragma unroll
      for (int j = 0; j < 8; ++j) {
        atomicAdd(&sbn[f * 8 + j], sv[j]);
        atomicAdd(&sbn[16 + f * 8 + j], qv[j]);
      }
    }
    __syncthreads();
    if (t < 16) atomicAdd(&bnsum[t], sbn[t]);
    else if (t < 32) atomicAdd(&bnsq[t - 16], sbn[t]);
  }
}

// ---------------- BN(from raw sums) + 16x16 matmul + a_s/a_d for layer 2 ----
// k_bnp folded in: each block recomputes scale/shift from bnsum/bnsq (L2-hot).
__global__ __launch_bounds__(256) void k_node2(
    const float* __restrict__ outv,
    const float* __restrict__ bnsum, const float* __restrict__ bnsq,
    const float* __restrict__ g1, const float* __restrict__ bb1, float invn,
    const float* __restrict__ W2,
    const float* __restrict__ asw, const float* __restrict__ adw,
    __half* __restrict__ hh, float* __restrict__ a_s, float* __restrict__ a_d, int n) {
  __shared__ float w2s[C * C];
  __shared__ float sc[C], sh[C];
  if (threadIdx.x < C * C) w2s[threadIdx.x] = W2[threadIdx.x];
  if (threadIdx.x < C) {
    int c = threadIdx.x;
    float mean = bnsum[c] * invn;
    float var = bnsq[c] * invn - mean * mean;
    float s = g1[c] * rsqrtf(var + 1e-5f);
    sc[c] = s; sh[c] = bb1[c] - mean * s;
  }
  __syncthreads();
  int i = blockIdx.x * 256 + threadIdx.x;
  if (i >= n) return;
  float hn[C];
  #pragma unroll
  for (int c = 0; c < C; ++c) hn[c] = outv[(size_t)i * C + c] * sc[c] + sh[c];
  float h2[C];
  #pragma unroll
  for (int j = 0; j < C; ++j) {
    float acc = 0.f;
    #pragma unroll
    for (int c = 0; c < C; ++c) acc += hn[c] * w2s[c * C + j];
    h2[j] = acc;
  }
  float hs = 0.f, hd = 0.f;
  #pragma unroll
  for (int j = 0; j < C; ++j) { hs += h2[j] * asw[j]; hd += h2[j] * adw[j]; }
  a_s[i] = hs; a_d[i] = hd;
  unsigned wbits[8];
  #pragma unroll
  for (int j = 0; j < 8; ++j) {
    __half2 hq = __floats2half2_rn(h2[2 * j], h2[2 * j + 1]);
    memcpy(&wbits[j], &hq, 4);
  }
  uint4* hp = (uint4*)(hh + (size_t)i * 16);
  hp[0] = make_uint4(wbits[0], wbits[1], wbits[2], wbits[3]);
  hp[1] = make_uint4(wbits[4], wbits[5], wbits[6], wbits[7]);
}

// ---------------- per-graph mean (gstart folded in: on-the-fly bin search) --
__global__ __launch_bounds__(256) void k_xe(
    const float* __restrict__ outv, const int* __restrict__ batch,
    float* __restrict__ xe, int n, int B_) {
  int wave = blockIdx.x * 4 + (threadIdx.x >> 6);
  if (wave >= B_) return;
  int lane = threadIdx.x & 63;
  int c = lane & 15, sub = lane >> 4;
  // lower_bound(batch, wave) and lower_bound(batch, wave+1), redundant per lane
  int lo = 0, hi = n;
  while (lo < hi) { int mid = (lo + hi) >> 1; if (batch[mid] < wave) lo = mid + 1; else hi = mid; }
  int base = lo;
  hi = n;
  while (lo < hi) { int mid = (lo + hi) >> 1; if (batch[mid] < wave + 1) lo = mid + 1; else hi = mid; }
  int end = lo;
  float s = 0.f;
  for (int n0 = base + sub; n0 < end; n0 += 4) s += outv[(size_t)n0 * C + c];
  s += __shfl_down(s, 32);
  s += __shfl_down(s, 16);
  if (lane < 16) xe[(size_t)wave * C + c] = s / fmaxf((float)(end - base), 1.f);
}

// ---------------- D2RL tail ----------------
__global__ __launch_bounds__(512) void k_tail_z3(
    const float* __restrict__ xe_in,
    const float* __restrict__ gL1, const float* __restrict__ bL1,
    const float* __restrict__ Wl1, const float* __restrict__ bl1,
    const float* __restrict__ gL2, const float* __restrict__ bL2,
    const float* __restrict__ Wl2, const float* __restrict__ bl2,
    const float* __restrict__ gL3, const float* __restrict__ bL3,
    const float* __restrict__ Wl3, const float* __restrict__ bl3,
    float* __restrict__ z3buf, int B_) {
  __shared__ float ssum[2 * C], ssq[2 * C], sc[2 * C], sh[2 * C];
  int t = threadIdx.x;
  float invB = 1.f / (float)B_;
  float xe[C];
  #pragma unroll
  for (int c = 0; c < C; ++c) xe[c] = xe_in[(size_t)t * C + c];

  if (t < 2 * C) { ssum[t] = 0.f; ssq[t] = 0.f; }
  __syncthreads();
  #pragma unroll
  for (int c = 0; c < C; ++c) {
    float s = xe[c], q = xe[c] * xe[c];
    for (int o = 32; o > 0; o >>= 1) { s += __shfl_down(s, o); q += __shfl_down(q, o); }
    if ((t & 63) == 0) { atomicAdd(&ssum[c], s); atomicAdd(&ssq[c], q); }
  }
  __syncthreads();
  if (t < C) {
    float mean = ssum[t] * invB, var = ssq[t] * invB - mean * mean;
    float s = gL1[t] * rsqrtf(var + 1e-5f);
    sc[t] = s; sh[t] = bL1[t] - mean * s;
  }
  __syncthreads();
  float z[C];
  #pragma unroll
  for (int j = 0; j < C; ++j) {
    float acc = bl1[j];
    #pragma unroll
    for (int c = 0; c < C; ++c) acc += (xe[c] * sc[c] + sh[c]) * Wl1[c * C + j];
    z[j] = fmaxf(acc, 0.f);
  }
  __syncthreads();

  if (t < 2 * C) { ssum[t] = 0.f; ssq[t] = 0.f; }
  __syncthreads();
  #pragma unroll
  for (int c = 0; c < C; ++c) {
    float s = z[c], q = z[c] * z[c];
    for (int o = 32; o > 0; o >>= 1) { s += __shfl_down(s, o); q += __shfl_down(q, o); }
    if ((t & 63) == 0) { atomicAdd(&ssum[c], s); atomicAdd(&ssq[c], q); }
    float s2 = xe[c], q2 = xe[c] * xe[c];
    for (int o = 32; o > 0; o >>= 1) { s2 += __shfl_down(s2, o); q2 += __shfl_down(q2, o); }
    if ((t & 63) == 0) { atomicAdd(&ssum[C + c], s2); atomicAdd(&ssq[C + c], q2); }
  }
  __syncthreads();
  if (t < 2 * C) {
    float mean = ssum[t] * invB, var = ssq[t] * invB - mean * mean;
    float s = gL2[t] * rsqrtf(var + 1e-5f);
    sc[t] = s; sh[t] = bL2[t] - mean * s;
  }
  __syncthreads();
  float z2[C];
  #pragma unroll
  for (int j = 0; j < C; ++j) {
    float acc = bl2[j];
    #pragma unroll
    for (int c = 0; c < C; ++c) acc += (z[c] * sc[c] + sh[c]) * Wl2[c * C + j];
    #pragma unroll
    for (int c = 0; c < C; ++c) acc += (xe[c] * sc[C + c] + sh[C + c]) * Wl2[(C + c) * C + j];
    z2[j] = fmaxf(acc, 0.f);
  }
  __syncthreads();

  if (t < 2 * C) { ssum[t] = 0.f; ssq[t] = 0.f; }
  __syncthreads();
  #pragma unroll
  for (int c = 0; c < C; ++c) {
    float s = z2[c], q = z2[c] * z2[c];
    for (int o = 32; o > 0; o >>= 1) { s += __shfl_down(s, o); q += __shfl_down(q, o); }
    if ((t & 63) == 0) { atomicAdd(&ssum[c], s); atomicAdd(&ssq[c], q); }
    float s2 = xe[c], q2 = xe[c] * xe[c];
    for (int o = 32; o > 0; o >>= 1) { s2 += __shfl_down(s2, o); q2 += __shfl_down(q2, o); }
    if ((t & 63) == 0) { atomicAdd(&ssum[C + c], s2); atomicAdd(&ssq[C + c], q2); }
  }
  __syncthreads();
  if (t < 2 * C) {
    float mean = ssum[t] * invB, var = ssq[t] * invB - mean * mean;
    float s = gL3[t] * rsqrtf(var + 1e-5f);
    sc[t] = s; sh[t] = bL3[t] - mean * s;
  }
  __syncthreads();
  #pragma unroll
  for (int j = 0; j < C; ++j) {
    float acc = bl3[j];
    #pragma unroll
    for (int c = 0; c < C; ++c) acc += (z2[c] * sc[c] + sh[c]) * Wl3[c * C + j];
    #pragma unroll
    for (int c = 0; c < C; ++c) acc += (xe[c] * sc[C + c] + sh[C + c]) * Wl3[(C + c) * C + j];
    z3buf[(size_t)t * C + j] = fmaxf(acc, 0.f);
  }
}

// ---------------- heads ----------------
__global__ __launch_bounds__(256) void k_heads(
    const float* __restrict__ z3buf,
    const float* __restrict__ Wx, const float* __restrict__ bx,
    const float* __restrict__ Wy, const float* __restrict__ by,
    const float* __restrict__ Wr, const float* __restrict__ br,
    float* __restrict__ out, int B_) {
  int wv = blockIdx.x * 4 + (threadIdx.x >> 6);
  if (wv >= B_) return;
  int lane = threadIdx.x & 63;
  float z[C];
  #pragma unroll
  for (int c = 0; c < C; ++c) z[c] = z3buf[(size_t)wv * C + c];

  float ax = bx[lane];
  #pragma unroll
  for (int c = 0; c < C; ++c) ax += z[c] * Wx[c * 64 + lane];
  float m = ax;
  #pragma unroll
  for (int o = 32; o > 0; o >>= 1) m = fmaxf(m, __shfl_xor(m, o));
  float e = __expf(ax - m);
  float s = e;
  #pragma unroll
  for (int o = 32; o > 0; o >>= 1) s += __shfl_xor(s, o);
  out[(size_t)wv * 64 + lane] = e / s;

  float ay = by[lane];
  #pragma unroll
  for (int c = 0; c < C; ++c) ay += z[c] * Wy[c * 64 + lane];
  m = ay;
  #pragma unroll
  for (int o = 32; o > 0; o >>= 1) m = fmaxf(m, __shfl_xor(m, o));
  e = __expf(ay - m);
  s = e;
  #pragma unroll
  for (int o = 32; o > 0; o >>= 1) s += __shfl_xor(s, o);
  out[(size_t)B_ * 64 + (size_t)wv * 64 + lane] = e / s;

  if (lane < 4) {
    float ar = br[lane];
    #pragma unroll
    for (int c = 0; c < C; ++c) ar += z[c] * Wr[c * 4 + lane];
    float mr = ar;
    mr = fmaxf(mr, __shfl_xor(mr, 1));
    mr = fmaxf(mr, __shfl_xor(mr, 2));
    float er = __expf(ar - mr);
    float sr = er;
    sr += __shfl_xor(sr, 1);
    sr += __shfl_xor(sr, 2);
    out[(size_t)B_ * 128 + (size_t)wv * 4 + lane] = er / sr;
  }
}

extern "C" void kernel_launch(void* const* d_in, const int* in_sizes, int n_in,
                              void* d_out, int out_size, void* d_ws, size_t ws_size,
                              hipStream_t stream) {
  const float* x     = (const float*)d_in[0];
  const int*   eidx  = (const int*)d_in[1];
  const float* eattr = (const float*)d_in[2];
  const int*   batch = (const int*)d_in[3];
  const float* W1  = (const float*)d_in[4];
  const float* We1 = (const float*)d_in[5];
  const float* as1 = (const float*)d_in[6];
  const float* ad1 = (const float*)d_in[7];
  const float* ae1 = (const float*)d_in[8];
  const float* b1  = (const float*)d_in[9];
  const float* g1  = (const float*)d_in[10];
  const float* bb1 = (const float*)d_in[11];
  const float* W2  = (const float*)d_in[12];
  const float* We2 = (const float*)d_in[13];
  const float* as2 = (const float*)d_in[14];
  const float* ad2 = (const float*)d_in[15];
  const float* ae2 = (const float*)d_in[16];
  const float* b2  = (const float*)d_in[17];
  const float* gL1 = (const float*)d_in[18];
  const float* bL1 = (const float*)d_in[19];
  const float* Wl1 = (const float*)d_in[20];
  const float* bl1 = (const float*)d_in[21];
  const float* gL2 = (const float*)d_in[22];
  const float* bL2 = (const float*)d_in[23];
  const float* Wl2 = (const float*)d_in[24];
  const float* bl2 = (const float*)d_in[25];
  const float* gL3 = (const float*)d_in[26];
  const float* bL3 = (const float*)d_in[27];
  const float* Wl3 = (const float*)d_in[28];
  const float* bl3 = (const float*)d_in[29];
  const float* Wx  = (const float*)d_in[30];
  const float* bx  = (const float*)d_in[31];
  const float* Wy  = (const float*)d_in[32];
  const float* by  = (const float*)d_in[33];
  const float* Wr  = (const float*)d_in[34];
  const float* br  = (const float*)d_in[35];

  int N = in_sizes[3];
  int E = in_sizes[2] / 2;
  int B = out_size / 132;

  const int* src = eidx;
  const int* dst = eidx + E;

  const int G = 256;                       // partition blocks (r6 champion)
  int nbin = (N + 255) >> 8;               // coarse bins (dst>>8)
  int nscan = nbin * G;
  int chunk = (E + G - 1) / G;
  int nblk2 = (nscan + 511) / 512;

  // ---- layout ----
  char* w = (char*)d_ws;
  size_t o = 0;
  auto alloc = [&](size_t bytes) { char* p = w + o; o += (bytes + 15) & ~15ull; return p; };
  uint2*  bucket = (uint2*)alloc((size_t)E * 8);
  uint2*  tmpR   = (uint2*)alloc((size_t)E * 8);
  int*    tmpD   = (int*)alloc((size_t)E * 4);
  __half* hh     = (__half*)alloc((size_t)N * C * 2);
  float*  outv   = (float*)alloc((size_t)N * C * 4);
  float*  a_s    = (float*)alloc((size_t)N * 4);
  float*  a_d    = (float*)alloc((size_t)N * 4);
  int*    counts = (int*)alloc((size_t)(N + 4) * 4);
  int*    offs   = (int*)alloc((size_t)(N + 4) * 4);
  int*    histT  = (int*)alloc((size_t)(nscan + 4) * 4);
  int*    histS  = (int*)alloc((size_t)(nscan + 4) * 4);
  int*    bsum   = (int*)alloc((size_t)(nblk2 + 516) * 4);
  float*  bn     = (float*)alloc(64 * 4);
  float*  xe     = (float*)alloc((size_t)B * C * 4);
  float*  z3buf  = (float*)alloc((size_t)B * C * 4);
  size_t need = o;

  bool radix = (need <= ws_size) && (nbin <= 512) && (nblk2 <= 512);

  hipMemsetAsync(bn, 0, 32 * 4, stream);
  k_gemm1<<<(N + 63) / 64, 256, 0, stream>>>(x, W1, as1, ad1, hh, a_s, a_d, N);

  if (radix) {
    k_p1count<<<G, 256, 0, stream>>>(dst, histT, E, chunk, G, nbin);
    k_scan1<<<nblk2, 512, 0, stream>>>(histT, bsum, nscan);
    k_scan2<<<1, 512, 0, stream>>>(bsum, histS, nblk2, nscan);
    k_scan3<<<nblk2, 512, 0, stream>>>(histT, bsum, histS, nscan);
    k_p1scat<<<G, 256, 0, stream>>>(src, dst, (const float2*)eattr, histS,
                                    We1, ae1, We2, ae2, tmpR, tmpD, E, chunk, G, nbin);
    k_p2<<<nbin, 256, 0, stream>>>(tmpR, tmpD, histS, bucket, offs, G, nbin, N, E);
  } else {
    int* rank = (int*)tmpR;
    int nblk = (N + 511) / 512;
    int ebl = (E + 255) / 256;
    hipMemsetAsync(counts, 0, (size_t)N * 4, stream);
    k_hist_rank<<<ebl, 256, 0, stream>>>(dst, counts, rank, E);
    k_scan1<<<nblk, 512, 0, stream>>>(counts, bsum, N);
    k_scan2<<<1, 512, 0, stream>>>(bsum, offs, nblk, N);
    k_scan3<<<nblk, 512, 0, stream>>>(counts, bsum, offs, N);
    k_scatter<<<ebl, 256, 0, stream>>>(src, dst, (const float2*)eattr, offs, rank,
                                       We1, ae1, We2, ae2, bucket, E);
  }

  int nbl = (N + 255) / 256;
  k_gather<<<(N + 63) / 64, 256, 0, stream>>>(bucket, offs, a_s, a_d, hh, b1,
                                              outv, bn, bn + 16, 0, 1, N);
  k_node2<<<nbl, 256, 0, stream>>>(outv, bn, bn + 16, g1, bb1, 1.f / (float)N,
                                   W2, as2, ad2, hh, a_s, a_d, N);
  k_gather<<<(N + 63) / 64, 256, 0, stream>>>(bucket, offs, a_s, a_d, hh, b2,
                                              outv, bn, bn + 16, 1, 0, N);
  k_xe<<<(B + 3) / 4, 256, 0, stream>>>(outv, batch, xe, N, B);
  k_tail_z3<<<1, B, 0, stream>>>(xe, gL1, bL1, Wl1, bl1, gL2, bL2, Wl2, bl2,
                                 gL3, bL3, Wl3, bl3, z3buf, B);
  k_heads<<<(B + 3) / 4, 256, 0, stream>>>(z3buf, Wx, bx, Wy, by, Wr, br,
                                           (float*)d_out, B);
}